// Round 5
// baseline (551.253 us; speedup 1.0000x reference)
//
#include <hip/hip_runtime.h>
#include <hip/hip_bf16.h>

// Problem constants (fixed by setup_inputs)
#define B_    4
#define N_    16384
#define D_    256
#define LD_   64
#define HID_  1024
#define HW_   128          // H = W = 128
#define HSRC_ 512
#define CS_   3
#define KIN_  320          // D_ + LD_

typedef __attribute__((ext_vector_type(8))) short bf16x8;
typedef __attribute__((ext_vector_type(4))) float f32x4;

__device__ __forceinline__ float wsum(float v) {
#pragma unroll
  for (int off = 32; off; off >>= 1) v += __shfl_xor(v, off, 64);
  return v;
}

// fp32 -> bf16 round-to-nearest-even (finite inputs)
__device__ __forceinline__ unsigned short f2bf(float f) {
  unsigned int u = __float_as_uint(f);
  u = (u + 0x7fffu + ((u >> 16) & 1u)) >> 16;
  return (unsigned short)u;
}
__device__ __forceinline__ float b2f(unsigned short u) {
  return __uint_as_float(((unsigned int)u) << 16);
}

// fast exact-ish gelu: tanh form, max err ~3e-4 (below bf16 quantum of h)
__device__ __forceinline__ float gelu_f(float x) {
  float z = 0.7978845608028654f * (x + 0.044715f * x * x * x);
  float e = __expf(2.0f * z);
  float th = 1.0f - 2.0f / (e + 1.0f);  // tanh(z), overflow-safe
  return 0.5f * x * (1.0f + th);
}

// async global->LDS direct copy, 16 bytes per lane (global_load_lds_dwordx4)
__device__ __forceinline__ void async16(unsigned short* lds, const unsigned short* g) {
  __builtin_amdgcn_global_load_lds(
      (const __attribute__((address_space(1))) unsigned int*)g,
      (__attribute__((address_space(3))) unsigned int*)lds, 16, 0, 0);
}

// ---------------------------------------------------------------------------
// K0: convert fc1_w (320,1024) -> Bt1 (1024,320) bf16; fc2_w (1024,256) -> Bt2 (256,1024) bf16
__global__ __launch_bounds__(256) void k_wconv(const float* __restrict__ fc1w,
                                               const float* __restrict__ fc2w,
                                               unsigned short* __restrict__ bt1,
                                               unsigned short* __restrict__ bt2) {
  int i = blockIdx.x * 256 + threadIdx.x;
  if (i < KIN_ * HID_) {
    int n = i / KIN_, k = i % KIN_;
    bt1[i] = f2bf(fc1w[(size_t)k * HID_ + n]);
  } else {
    int j = i - KIN_ * HID_;
    if (j < D_ * HID_) {
      int n = j / HID_, k = j % HID_;
      bt2[j] = f2bf(fc2w[(size_t)k * D_ + n]);
    }
  }
}

// ---------------------------------------------------------------------------
// K2: fused — LN(x)@w_delta -> loc_extra; out1 = [loc, loc_extra];
//     out0 first half = x (copy); per-cell linked list build (head/nxt).
__global__ __launch_bounds__(256) void k_delta(const float* __restrict__ x,
                                               const float* __restrict__ loc,
                                               const float* __restrict__ wd,
                                               const float* __restrict__ bd,
                                               const float* __restrict__ g1,
                                               const float* __restrict__ b1,
                                               float* __restrict__ locex,
                                               float* __restrict__ out1,
                                               float* __restrict__ out0,
                                               int* __restrict__ head,
                                               int* __restrict__ nxt) {
  int wv = threadIdx.x >> 6, lane = threadIdx.x & 63;
  int t = blockIdx.x * 4 + wv;
  int b = t >> 14, n = t & (N_ - 1);
  const float4 xv = *(const float4*)(x + (size_t)t * D_ + lane * 4);
  // copy x into out0 first half
  *(float4*)(out0 + ((size_t)b * 2 * N_ + n) * D_ + lane * 4) = xv;
  float m = wsum(xv.x + xv.y + xv.z + xv.w) * (1.0f / D_);
  float d0 = xv.x - m, d1 = xv.y - m, d2 = xv.z - m, d3 = xv.w - m;
  float v = wsum(d0 * d0 + d1 * d1 + d2 * d2 + d3 * d3) * (1.0f / D_);
  float r = rsqrtf(v + 1e-5f);
  const float4 gv = *(const float4*)(g1 + lane * 4);
  const float4 bv = *(const float4*)(b1 + lane * 4);
  float n0 = d0 * r * gv.x + bv.x;
  float n1 = d1 * r * gv.y + bv.y;
  float n2 = d2 * r * gv.z + bv.z;
  float n3 = d3 * r * gv.w + bv.w;
  int i2 = lane * 8;  // (lane*4)*2
  float p0 = n0 * wd[i2 + 0] + n1 * wd[i2 + 2] + n2 * wd[i2 + 4] + n3 * wd[i2 + 6];
  float p1 = n0 * wd[i2 + 1] + n1 * wd[i2 + 3] + n2 * wd[i2 + 5] + n3 * wd[i2 + 7];
  p0 = wsum(p0);
  p1 = wsum(p1);
  if (lane == 0) {
    float lx = loc[(size_t)t * 2], ly = loc[(size_t)t * 2 + 1];
    float ex = fminf(fmaxf(lx + (p0 + bd[0]) * 0.01f, 0.0f), 1.0f);
    float ey = fminf(fmaxf(ly + (p1 + bd[1]) * 0.01f, 0.0f), 1.0f);
    locex[(size_t)t * 2] = ex;
    locex[(size_t)t * 2 + 1] = ey;
    size_t o1 = (size_t)b * 2 * N_;
    out1[(o1 + n) * 2 + 0] = lx;
    out1[(o1 + n) * 2 + 1] = ly;
    out1[(o1 + N_ + n) * 2 + 0] = ex;
    out1[(o1 + N_ + n) * 2 + 1] = ey;
    // token2map linked-list build (uses raw loc)
    float cx = fminf(fmaxf(lx, 0.0f), 1.0f) * 127.0f;
    float cy = fminf(fmaxf(ly, 0.0f), 1.0f) * 127.0f;
    int ix = (int)rintf(cx);  // round-half-even, matches jnp.round
    int iy = (int)rintf(cy);
    int cell = (b << 14) + iy * HW_ + ix;
    nxt[t] = atomicExch(head + cell, t);
  }
}

// ---------------------------------------------------------------------------
// K3b: one block per cell — walk token list, sum x, write NORMALIZED feat (bf16) + cnt.
__global__ __launch_bounds__(256) void k_gather(const float* __restrict__ x,
                                                const int* __restrict__ head,
                                                const int* __restrict__ nxt,
                                                unsigned short* __restrict__ featn,
                                                float* __restrict__ cntf) {
  int cell = blockIdx.x;
  int tid = threadIdx.x;
  __shared__ int toks[16];
  __shared__ int scount, snext;
  float acc = 0.0f;
  int total = 0;
  int cur = head[cell];
  while (cur >= 0) {
    if (tid == 0) {
      int c = 0, p = cur;
      while (p >= 0 && c < 16) {
        toks[c++] = p;
        p = nxt[p];
      }
      scount = c;
      snext = p;
    }
    __syncthreads();
    int c = scount;
    for (int i = 0; i < c; ++i) acc += x[(size_t)toks[i] * D_ + tid];
    total += c;
    cur = snext;
    __syncthreads();
  }
  featn[(size_t)cell * D_ + tid] = f2bf((total > 0) ? acc / ((float)total + 1e-6f) : 0.0f);
  if (tid == 0) cntf[cell] = (float)total;
}

// ---------------------------------------------------------------------------
// K4: gaussian inpaint (3x3, sigma=2) over normalized feat -> fmap (bf16, channel-last)
__global__ __launch_bounds__(256) void k_filter(const unsigned short* __restrict__ featn,
                                                const float* __restrict__ cntf,
                                                unsigned short* __restrict__ fmap) {
  int pix = blockIdx.x;  // b*16384 + y*128 + x
  int c = threadIdx.x;
  int b = pix >> 14;
  int p = pix & 16383;
  int y = p >> 7, xc = p & 127;
  float cc = cntf[pix];
  unsigned short outv;
  if (cc > 0.0f) {
    outv = featn[(size_t)pix * D_ + c];
  } else {
    float e1 = expf(-0.125f), e2 = expf(-0.25f);
    float sumw = 1.0f + 4.0f * e1 + 4.0f * e2;
    float gf = 0.0f, gm = 0.0f;
#pragma unroll
    for (int dy = -1; dy <= 1; ++dy)
#pragma unroll
      for (int dx = -1; dx <= 1; ++dx) {
        int ny = y + dy, nx = xc + dx;
        if (ny < 0 || ny >= HW_ || nx < 0 || nx >= HW_) continue;
        int q = (b << 14) + ny * HW_ + nx;
        if (cntf[q] > 0.0f) {
          int dd = dy * dy + dx * dx;
          float w = (dd == 0 ? 1.0f : (dd == 1 ? e1 : e2)) / sumw;
          gf += w * b2f(featn[(size_t)q * D_ + c]);
          gm += w;
        }
      }
    outv = f2bf((gm > 0.0f) ? gf / (gm + 1e-6f) : 0.0f);
  }
  fmap[(size_t)pix * D_ + c] = outv;
}

// ---------------------------------------------------------------------------
// K5: 4x4 patch bilinear sample from src + conv (64,3,4,4) + LN(64)
//     writes extra_cat[:, 256:320] as bf16. One wave per token.
__global__ __launch_bounds__(256) void k_patch(const float* __restrict__ src,
                                               const float* __restrict__ locex,
                                               const float* __restrict__ convw,
                                               const float* __restrict__ convb,
                                               const float* __restrict__ g2,
                                               const float* __restrict__ b2,
                                               unsigned short* __restrict__ ecat) {
  __shared__ float cw[LD_ * 49];
  __shared__ float patch[4][48];
  for (int i = threadIdx.x; i < LD_ * 48; i += 256)
    cw[(i / 48) * 49 + (i % 48)] = convw[i];
  int wv = threadIdx.x >> 6, lane = threadIdx.x & 63;
  int t = blockIdx.x * 4 + wv;
  int b = t >> 14;
  float ex = locex[(size_t)t * 2], ey = locex[(size_t)t * 2 + 1];
  __syncthreads();
  if (lane < 48) {
    int c = lane >> 4, p = lane & 15, py = p >> 2, px = p & 3;
    float u = ex + ((float)px - 1.5f) / 511.0f;
    float vv = ey + ((float)py - 1.5f) / 511.0f;
    float gx = u * 512.0f - 0.5f;
    float gy = vv * 512.0f - 0.5f;
    float fx = floorf(gx), fy = floorf(gy);
    float wx = gx - fx, wy = gy - fy;
    int x0 = (int)fx, y0 = (int)fy;
    const float* plane = src + (size_t)(b * CS_ + c) * (HSRC_ * HSRC_);
    float acc = 0.0f;
#pragma unroll
    for (int ty = 0; ty < 2; ++ty)
#pragma unroll
      for (int tx = 0; tx < 2; ++tx) {
        int xi = x0 + tx, yi = y0 + ty;
        float w = (tx ? wx : 1.0f - wx) * (ty ? wy : 1.0f - wy);
        if (xi >= 0 && xi < HSRC_ && yi >= 0 && yi < HSRC_)
          acc += w * plane[yi * HSRC_ + xi];
      }
    patch[wv][lane] = acc;
  }
  __syncthreads();
  float e = convb[lane];
#pragma unroll
  for (int i = 0; i < 48; ++i) e += patch[wv][i] * cw[lane * 49 + i];
  float m = wsum(e) * (1.0f / 64.0f);
  float d = e - m;
  float v = wsum(d * d) * (1.0f / 64.0f);
  float val = d * rsqrtf(v + 1e-5f) * g2[lane] + b2[lane];
  ecat[(size_t)t * KIN_ + D_ + lane] = f2bf(val);
}

// ---------------------------------------------------------------------------
// K6: bilinear sample fmap (bf16) at loc_extra -> extra_cat[:, 0:256] bf16. Wave/token.
__global__ __launch_bounds__(256) void k_sample(const unsigned short* __restrict__ fmap,
                                                const float* __restrict__ locex,
                                                unsigned short* __restrict__ ecat) {
  int wv = threadIdx.x >> 6, lane = threadIdx.x & 63;
  int t = blockIdx.x * 4 + wv;
  int b = t >> 14;
  float gx = locex[(size_t)t * 2] * 128.0f - 0.5f;
  float gy = locex[(size_t)t * 2 + 1] * 128.0f - 0.5f;
  float fx = floorf(gx), fy = floorf(gy);
  float wx = gx - fx, wy = gy - fy;
  int x0 = (int)fx, y0 = (int)fy;
  const unsigned short* base = fmap + (((size_t)b << 14)) * D_;
  float4 acc = {0.0f, 0.0f, 0.0f, 0.0f};
#pragma unroll
  for (int ty = 0; ty < 2; ++ty)
#pragma unroll
    for (int tx = 0; tx < 2; ++tx) {
      int xi = x0 + tx, yi = y0 + ty;
      float w = (tx ? wx : 1.0f - wx) * (ty ? wy : 1.0f - wy);
      if (xi >= 0 && xi < HW_ && yi >= 0 && yi < HW_) {
        ushort4 f = *(const ushort4*)(base + (size_t)(yi * HW_ + xi) * D_ + lane * 4);
        acc.x += w * b2f(f.x);
        acc.y += w * b2f(f.y);
        acc.z += w * b2f(f.z);
        acc.w += w * b2f(f.w);
      }
    }
  ushort4 o;
  o.x = f2bf(acc.x);
  o.y = f2bf(acc.y);
  o.z = f2bf(acc.z);
  o.w = f2bf(acc.w);
  *(ushort4*)(ecat + (size_t)t * KIN_ + lane * 4) = o;
}

// ---------------------------------------------------------------------------
// K7: FUSED MLP — out0.extra = gelu(ecat@W1 + b1) @ W2 + b2, h never hits HBM.
// Block = 64 token rows, 4 waves. Wave wv owns token rows [16wv,16wv+16).
// A (64x320 ecat) loaded once into registers (10 bf16x8/lane).
// Loop t over 8 hidden 128-col tiles:
//   - gemm1: 5 K-iters streaming bt1 tiles (128x64) through 2x16KB LDS dbuf
//     with the proven counted-vmcnt(4) 2-phase pipeline -> acc1 (h-tile 64x128)
//   - gelu -> bf16 -> XOR-swizzled 16KB hbuf
//   - gemm2: 4 k2-steps vs bt2 fragments from global (L2-resident) -> acc2
// Epilogue: acc2 + fc2b -> out0 extra half (64B-segment stores).
// Traffic: read ecat 40MB once + weights; write 67MB. (was ~470MB across 2 GEMMs)
__global__ __launch_bounds__(256, 2) void k_mlp(const unsigned short* __restrict__ ecat,
                                                const unsigned short* __restrict__ bt1,
                                                const unsigned short* __restrict__ bt2,
                                                const float* __restrict__ fc1b,
                                                const float* __restrict__ fc2b,
                                                float* __restrict__ out0) {
  // LDS: bt1 dbuf 2x8192 shorts at 0 / 8192; hbuf 8192 shorts at 16384. 48KB.
  __shared__ __align__(16) unsigned short sh[24576];
  int tid = threadIdx.x, wv = tid >> 6, lane = tid & 63;
  int hi = lane >> 4, lo = lane & 15, sw = lane & 7;

  int tile_m = blockIdx.x * 64;

  // ---- A into registers: a[kk] = ecat[tile_m+16wv+lo][kk*32 + hi*8 .. +8)
  bf16x8 a[10];
  {
    const unsigned short* arow = ecat + (size_t)(tile_m + wv * 16 + lo) * KIN_ + hi * 8;
#pragma unroll
    for (int kk = 0; kk < 10; ++kk) a[kk] = *(const bf16x8*)(arow + kk * 32);
  }

  f32x4 acc2[4][4];
#pragma unroll
  for (int i = 0; i < 4; ++i)
#pragma unroll
    for (int j = 0; j < 4; ++j) acc2[i][j] = (f32x4){0.0f, 0.0f, 0.0f, 0.0f};

  // prologue: stage bt1 tile (t=0,k0=0) into buf0.
  // chunk L (0..1023): line=L>>3 holds global 16B-chunk (L&7)^(line&7) at slot L&7.
#pragma unroll
  for (int c = 0; c < 4; ++c) {
    int L = c * 256 + tid;
    int line = L >> 3, u = (L & 7) ^ (line & 7);
    async16(sh + L * 8, bt1 + (size_t)line * KIN_ + u * 8);
  }
  int pt = 0, pk = 1;  // next (t,k0) tile to prefetch
  int cur = 0;         // current buffer short-offset: 0 or 8192

  for (int t = 0; t < 8; ++t) {
    f32x4 acc1[8];
#pragma unroll
    for (int i = 0; i < 8; ++i) acc1[i] = (f32x4){0.0f, 0.0f, 0.0f, 0.0f};

#pragma unroll
    for (int k0 = 0; k0 < 5; ++k0) {
      __builtin_amdgcn_sched_barrier(0);  // prefetch stays in its iteration
      if (!(t == 7 && k0 == 4)) {
        unsigned short* nb = sh + (cur ^ 8192);
        const unsigned short* gB = bt1 + (size_t)(pt * 128) * KIN_ + pk * 64;
#pragma unroll
        for (int c = 0; c < 4; ++c) {
          int L = c * 256 + tid;
          int line = L >> 3, u = (L & 7) ^ (line & 7);
          async16(nb + L * 8, gB + (size_t)line * KIN_ + u * 8);
        }
        if (++pk == 5) { pk = 0; ++pt; }
        asm volatile("s_waitcnt vmcnt(4)" ::: "memory");
      } else {
        asm volatile("s_waitcnt vmcnt(0)" ::: "memory");
      }
      __builtin_amdgcn_s_barrier();
      __builtin_amdgcn_sched_barrier(0);

      const unsigned short* Bs = sh + cur;
#pragma unroll
      for (int j = 0; j < 2; ++j) {
        bf16x8 bfr[8];
        int ca = ((j * 4 + hi) ^ sw) * 8;
#pragma unroll
        for (int nt = 0; nt < 8; ++nt)
          bfr[nt] = *(const bf16x8*)(Bs + (nt * 16 + lo) * 64 + ca);
        __builtin_amdgcn_s_setprio(1);
#pragma unroll
        for (int nt = 0; nt < 8; ++nt)
          acc1[nt] = __builtin_amdgcn_mfma_f32_16x16x32_bf16(a[k0 * 2 + j], bfr[nt],
                                                             acc1[nt], 0, 0, 0);
        __builtin_amdgcn_s_setprio(0);
      }
      __builtin_amdgcn_sched_barrier(0);
      __builtin_amdgcn_s_barrier();
      cur ^= 8192;
    }

    // gelu -> hbuf (64 rows x 128 shorts, 16B-chunk g stored at slot g^(row&7))
    unsigned short* hb = sh + 16384;
#pragma unroll
    for (int nt = 0; nt < 8; ++nt) {
      int col = nt * 16 + lo;               // local hidden col 0..127
      float bv = fc1b[t * 128 + col];
      int g = col >> 3;
#pragma unroll
      for (int r = 0; r < 4; ++r) {
        int m = wv * 16 + hi * 4 + r;       // local token row 0..63
        int slot = g ^ (m & 7);
        hb[m * 128 + slot * 8 + (col & 7)] = f2bf(gelu_f(acc1[nt][r] + bv));
      }
    }
    asm volatile("s_waitcnt lgkmcnt(0)" ::: "memory");
    __builtin_amdgcn_s_barrier();
    __builtin_amdgcn_sched_barrier(0);

    // gemm2: k2-slice [128t,128t+128) in 4 steps; b2 frags straight from L2.
#pragma unroll
    for (int s = 0; s < 4; ++s) {
      bf16x8 a2[4], b2[4];
#pragma unroll
      for (int mt = 0; mt < 4; ++mt) {
        int row = mt * 16 + lo;
        int slot = (s * 4 + hi) ^ (row & 7);
        a2[mt] = *(const bf16x8*)(hb + row * 128 + slot * 8);
      }
#pragma unroll
      for (int nt2 = 0; nt2 < 4; ++nt2) {
        int n2 = wv * 64 + nt2 * 16 + lo;
        b2[nt2] = *(const bf16x8*)(bt2 + (size_t)n2 * HID_ + t * 128 + s * 32 + hi * 8);
      }
      __builtin_amdgcn_s_setprio(1);
#pragma unroll
      for (int mt = 0; mt < 4; ++mt)
#pragma unroll
        for (int nt2 = 0; nt2 < 4; ++nt2)
          acc2[mt][nt2] = __builtin_amdgcn_mfma_f32_16x16x32_bf16(a2[mt], b2[nt2],
                                                                  acc2[mt][nt2], 0, 0, 0);
      __builtin_amdgcn_s_setprio(0);
    }
    __builtin_amdgcn_sched_barrier(0);
    // NOTE: next t's hbuf writes are ordered after >=2 rendezvous barriers in
    // the gemm1 phase, so no extra barrier needed here.
  }

  // epilogue: out0 extra half (fp32). 16-lane-consecutive dwords = 64B segments.
#pragma unroll
  for (int nt2 = 0; nt2 < 4; ++nt2) {
    int col = wv * 64 + nt2 * 16 + lo;
    float bv = fc2b[col];
#pragma unroll
    for (int mt = 0; mt < 4; ++mt) {
#pragma unroll
      for (int r = 0; r < 4; ++r) {
        int m = tile_m + mt * 16 + hi * 4 + r;
        int bb = m >> 14, ntok = m & (N_ - 1);
        out0[((size_t)bb * 2 * N_ + N_ + ntok) * D_ + col] = acc2[mt][nt2][r] + bv;
      }
    }
  }
}

// ---------------------------------------------------------------------------
extern "C" void kernel_launch(void* const* d_in, const int* in_sizes, int n_in,
                              void* d_out, int out_size, void* d_ws, size_t ws_size,
                              hipStream_t stream) {
  const float* x = (const float*)d_in[0];
  const float* loc = (const float*)d_in[1];
  const float* src = (const float*)d_in[2];
  const float* wd = (const float*)d_in[7];
  const float* bd = (const float*)d_in[8];
  const float* g1 = (const float*)d_in[9];
  const float* b1 = (const float*)d_in[10];
  const float* cw = (const float*)d_in[11];
  const float* cb = (const float*)d_in[12];
  const float* g2 = (const float*)d_in[13];
  const float* b2 = (const float*)d_in[14];
  const float* fc1w = (const float*)d_in[15];
  const float* fc1b = (const float*)d_in[16];
  const float* fc2w = (const float*)d_in[17];
  const float* fc2b = (const float*)d_in[18];

  float* out0 = (float*)d_out;
  float* out1 = out0 + (size_t)B_ * 2 * N_ * D_;

  char* ws = (char*)d_ws;
  // Workspace layout (bytes). h intermediate ELIMINATED (fused MLP).
  unsigned short* featn = (unsigned short*)(ws + 0);         //  33,554,432
  unsigned short* fmap = (unsigned short*)(ws + 33554432);   //  33,554,432
  unsigned short* ecat = (unsigned short*)(ws + 134217728);  //  41,943,040
  unsigned short* bt1 = (unsigned short*)(ws + 176160768);   //     655,360
  unsigned short* bt2 = (unsigned short*)(ws + 176816128);   //     524,288
  float* cntf = (float*)(ws + 177340416);                    //     262,144
  float* locex = (float*)(ws + 177602560);                   //     524,288
  int* head = (int*)(ws + 178126848);                        //     262,144
  int* nxt = (int*)(ws + 178388992);                         //     262,144

  hipMemsetAsync(head, 0xFF, (size_t)262144, stream);  // head[cell] = -1

  k_wconv<<<2304, 256, 0, stream>>>(fc1w, fc2w, bt1, bt2);
  k_delta<<<16384, 256, 0, stream>>>(x, loc, wd, bd, g1, b1, locex, out1, out0, head, nxt);
  k_gather<<<65536, 256, 0, stream>>>(x, head, nxt, featn, cntf);
  k_filter<<<65536, 256, 0, stream>>>(featn, cntf, fmap);
  k_patch<<<16384, 256, 0, stream>>>(src, locex, cw, cb, g2, b2, ecat);
  k_sample<<<16384, 256, 0, stream>>>(fmap, locex, ecat);
  k_mlp<<<1024, 256, 0, stream>>>(ecat, bt1, bt2, fc1b, fc2b, out0);
}